// Round 2
// baseline (10487.965 us; speedup 1.0000x reference)
//
#include <hip/hip_runtime.h>

// Only the temporal (LSTM) branch of the reference reaches the output
// (h_gcn is dead). Per node:
//   xt_s = x[n, 52+s] * W_tp + b_tp          (rank-1, folded into A0/C0)
//   2-layer LSTM (H=32, T=12, torch gate order i,f,g,o)
//   out[n] = relu(h1 @ W_fc1 + b_fc1) @ W_fc2 + b_fc2
//
// v3: 1 node per thread, ALL state (h0,h1,c0,c1) in registers via full
// unroll of the gate-row loops (static indices only -> no scratch, no
// per-thread LDS). Weight delivery split across two pipes:
//   - layer 0 (Whh0, 16 KB): scalar s_load path, K$-resident
//   - layer 1 (Wih1+Whh1, 32 KB): staged once into LDS, read as
//     uniform-address broadcast ds_read_b128 (base + imm offsets)
// LDS/block = 32 KB (weights only). __launch_bounds__(256,2) caps VGPR at
// 256 so the v2 spill disaster (forced 64-VGPR tier -> 15 GB scratch
// traffic) cannot recur. Expect ~190 VGPR -> 8 waves/CU.

#define TSTEPS 12
#define BS 256

__device__ __forceinline__ float fsig(float x) {
    float e = __expf(-x);                      // v_exp path; e in [0, inf)
    return __builtin_amdgcn_rcpf(1.0f + e);    // 1/(1+e), ~1 ulp
}

__device__ __forceinline__ float ftanh(float x) {
    float ax = fabsf(x);
    float e = __expf(-2.0f * ax);              // in (0,1], no overflow
    float r = (1.0f - e) * __builtin_amdgcn_rcpf(1.0f + e);
    return x < 0.0f ? -r : r;
}

// Fold layer-0 input matmul:
//   A0[r] = dot(Wih0[r,:], W_tp)          (scalar per gate row)
//   C0[r] = dot(Wih0[r,:], b_tp) + bih0[r] + bhh0[r]
//   C1[r] = bih1[r] + bhh1[r]
// ws layout: [0:128) A0, [128:256) C0, [256:384) C1
__global__ void precomp_kernel(const float* __restrict__ Wih0,
                               const float* __restrict__ Wtp,
                               const float* __restrict__ btp,
                               const float* __restrict__ bih0,
                               const float* __restrict__ bhh0,
                               const float* __restrict__ bih1,
                               const float* __restrict__ bhh1,
                               float* __restrict__ ws) {
    int r = threadIdx.x;   // 0..127
    if (r < 128) {
        float a = 0.0f, c = 0.0f;
#pragma unroll
        for (int k = 0; k < 16; ++k) {
            float w = Wih0[r * 16 + k];
            a += w * Wtp[k];
            c += w * btp[k];
        }
        ws[r]       = a;
        ws[128 + r] = c + bih0[r] + bhh0[r];
        ws[256 + r] = bih1[r] + bhh1[r];
    }
}

__global__ __launch_bounds__(BS, 2) void lstm_kernel(
    const float* __restrict__ x,
    const float* __restrict__ Whh0,   // [128,32]
    const float* __restrict__ Wih1,   // [128,32]
    const float* __restrict__ Whh1,   // [128,32]
    const float* __restrict__ Wfc1,   // [32,16]
    const float* __restrict__ bfc1,   // [16]
    const float* __restrict__ Wfc2,   // [16]
    const float* __restrict__ bfc2,   // [1]
    const float* __restrict__ pre,    // [384] from precomp
    float* __restrict__ out, int N)
{
    // Layer-1 weights, interleaved per gate-row j:
    //   sW1[j*256 + 0..127]   = Wih1 rows (j, j+32, j+64, j+96), 32 each
    //   sW1[j*256 + 128..255] = Whh1 rows (j, j+32, j+64, j+96), 32 each
    // Inner loop reads are uniform-address (broadcast) -> conflict-free,
    // and contiguous -> ds_read_b128 with immediate offsets off one base.
    __shared__ __align__(16) float sW1[8192];   // 32 KB

    const int tid = threadIdx.x;
    {
        const int half = tid >> 7;          // 0: Wih1, 1: Whh1
        const int g    = (tid >> 5) & 3;    // gate
        const int k    = tid & 31;          // column
        const float* src = half ? Whh1 : Wih1;
#pragma unroll
        for (int i = 0; i < 32; ++i)        // i = gate-row j
            sW1[i * 256 + tid] = src[(g * 32 + i) * 32 + k];
    }
    __syncthreads();                        // the only block barrier

    const int n  = blockIdx.x * BS + tid;
    const int nn = (n < N) ? n : (N > 0 ? N - 1 : 0);
    const float* xr = x + (size_t)nn * 64 + 52;   // last 12 features

    float h0[32], h1[32], c0[32], c1[32];
#pragma unroll
    for (int k = 0; k < 32; ++k) { h0[k] = 0.0f; h1[k] = 0.0f; c0[k] = 0.0f; c1[k] = 0.0f; }

#pragma unroll 1
    for (int t = 0; t < TSTEPS; ++t) {
        const float xv = xr[t];
        float nh[32];

        // ---------------- layer 0 (scalar-path weights) -----------------
#pragma unroll
        for (int j = 0; j < 32; ++j) {
            float gi = pre[128 + j] + xv * pre[j];
            float gf = pre[160 + j] + xv * pre[32 + j];
            float gg = pre[192 + j] + xv * pre[64 + j];
            float go = pre[224 + j] + xv * pre[96 + j];
            const float* w = Whh0 + j * 32;       // rows j, j+32, j+64, j+96
#pragma unroll
            for (int k = 0; k < 32; ++k) {
                const float hk = h0[k];
                gi += w[k]        * hk;
                gf += w[1024 + k] * hk;
                gg += w[2048 + k] * hk;
                go += w[3072 + k] * hk;
            }
            const float cc = fsig(gf) * c0[j] + fsig(gi) * ftanh(gg);
            c0[j] = cc;
            nh[j] = fsig(go) * ftanh(cc);
        }
#pragma unroll
        for (int k = 0; k < 32; ++k) h0[k] = nh[k];

        // ---------------- layer 1 (LDS broadcast weights) ----------------
#pragma unroll
        for (int j = 0; j < 32; ++j) {
            float gi = pre[256 + j];
            float gf = pre[288 + j];
            float gg = pre[320 + j];
            float go = pre[352 + j];
            const float* wj = &sW1[j * 256];
#pragma unroll
            for (int k = 0; k < 32; ++k) {
                const float ak = h0[k];
                const float bk = h1[k];
                gi += wj[k]       * ak + wj[128 + k] * bk;
                gf += wj[32 + k]  * ak + wj[160 + k] * bk;
                gg += wj[64 + k]  * ak + wj[192 + k] * bk;
                go += wj[96 + k]  * ak + wj[224 + k] * bk;
            }
            const float cc = fsig(gf) * c1[j] + fsig(gi) * ftanh(gg);
            c1[j] = cc;
            nh[j] = fsig(go) * ftanh(cc);
        }
#pragma unroll
        for (int k = 0; k < 32; ++k) h1[k] = nh[k];
    }

    // epilogue: relu(h1 @ Wfc1 + bfc1) @ Wfc2 + bfc2
    float acc = bfc2[0];
#pragma unroll 1
    for (int m = 0; m < 16; ++m) {
        float a = bfc1[m];
#pragma unroll
        for (int k = 0; k < 32; ++k) a += h1[k] * Wfc1[k * 16 + m];
        acc += fmaxf(a, 0.0f) * Wfc2[m];
    }
    if (n < N) out[n] = acc;
}

extern "C" void kernel_launch(void* const* d_in, const int* in_sizes, int n_in,
                              void* d_out, int out_size, void* d_ws, size_t ws_size,
                              hipStream_t stream) {
    (void)n_in; (void)out_size; (void)ws_size;
    // setup_inputs() order:
    // 0 x, 1 edge_index, 2 W_fp, 3 b_fp, 4 W_g1, 5 b_g1, 6 W_g2, 7 b_g2,
    // 8 W_g3, 9 b_g3, 10 W_tp, 11 b_tp, 12 Wih0, 13 Whh0, 14 bih0, 15 bhh0,
    // 16 Wih1, 17 Whh1, 18 bih1, 19 bhh1, 20 W_fc1, 21 b_fc1, 22 W_fc2, 23 b_fc2
    const float* x    = (const float*)d_in[0];
    const float* Wtp  = (const float*)d_in[10];
    const float* btp  = (const float*)d_in[11];
    const float* Wih0 = (const float*)d_in[12];
    const float* Whh0 = (const float*)d_in[13];
    const float* bih0 = (const float*)d_in[14];
    const float* bhh0 = (const float*)d_in[15];
    const float* Wih1 = (const float*)d_in[16];
    const float* Whh1 = (const float*)d_in[17];
    const float* bih1 = (const float*)d_in[18];
    const float* bhh1 = (const float*)d_in[19];
    const float* Wfc1 = (const float*)d_in[20];
    const float* bfc1 = (const float*)d_in[21];
    const float* Wfc2 = (const float*)d_in[22];
    const float* bfc2 = (const float*)d_in[23];

    float* out = (float*)d_out;
    float* pre = (float*)d_ws;   // 384 floats

    const int N = in_sizes[0] / 64;

    precomp_kernel<<<1, 128, 0, stream>>>(Wih0, Wtp, btp, bih0, bhh0, bih1, bhh1, pre);
    lstm_kernel<<<(N + BS - 1) / BS, BS, 0, stream>>>(
        x, Whh0, Wih1, Whh1, Wfc1, bfc1, Wfc2, bfc2, pre, out, N);
}

// Round 4
// 1979.934 us; speedup vs baseline: 5.2971x; 5.2971x over previous
//
#include <hip/hip_runtime.h>

// Only the temporal (LSTM) branch of the reference reaches the output
// (h_gcn is dead). Per node:
//   xt_s = x[n, 52+s] * W_tp + b_tp          (rank-1, folded into A0/C0)
//   2-layer LSTM (H=32, T=12, torch gate order i,f,g,o)
//   out[n] = relu(h1 @ W_fc1 + b_fc1) @ W_fc2 + b_fc2
//
// v4 = v2's cooperative structure with its two defects fixed:
//  - NO __launch_bounds__ min-waves floor (v2's (256,4) forced a 64-VGPR
//    allocation against ~104 regs of live state -> 15 GB scratch traffic).
//    Plain __launch_bounds__(BS) lets the allocator take ~110 VGPR like v1.
//  - jbase forced into an SGPR via readfirstlane, so weight addresses are
//    provably wave-uniform -> scalar s_load path (K$), not vector loads.
// Structure: 4 waves per block cooperate on the same 64 nodes; wave w
// computes gate rows j in [8w,8w+8). h-state replicated in registers
// (static indices); c-state partitioned in LDS columns (owner-only);
// new-h double-buffered in LDS (snhA layer0 / snhB layer1), one barrier
// per layer. LDS 32KB/block, expect 4 blocks/CU = 16 waves/CU.
// (Resubmission of round-3 kernel: bench failed on GPU acquisition,
// no measurement was taken.)

#define TSTEPS 12
#define NPB 64               // nodes per block
#define NW 4                 // waves per block
#define BS (NPB * NW)        // 256 threads
#define NJ (32 / NW)         // 8 gate-rows per wave

__device__ __forceinline__ float fsig(float x) {
    float e = __expf(-x);                      // v_exp path; e in [0, inf)
    return __builtin_amdgcn_rcpf(1.0f + e);    // 1/(1+e), ~1 ulp
}

__device__ __forceinline__ float ftanh(float x) {
    float ax = fabsf(x);
    float e = __expf(-2.0f * ax);              // in (0,1], no overflow
    float r = (1.0f - e) * __builtin_amdgcn_rcpf(1.0f + e);
    return x < 0.0f ? -r : r;
}

// Fold layer-0 input matmul:
//   A0[r] = dot(Wih0[r,:], W_tp)          (scalar per gate row)
//   C0[r] = dot(Wih0[r,:], b_tp) + bih0[r] + bhh0[r]
//   C1[r] = bih1[r] + bhh1[r]
// ws layout: [0:128) A0, [128:256) C0, [256:384) C1
__global__ void precomp_kernel(const float* __restrict__ Wih0,
                               const float* __restrict__ Wtp,
                               const float* __restrict__ btp,
                               const float* __restrict__ bih0,
                               const float* __restrict__ bhh0,
                               const float* __restrict__ bih1,
                               const float* __restrict__ bhh1,
                               float* __restrict__ ws) {
    int r = threadIdx.x;   // 0..127
    if (r < 128) {
        float a = 0.0f, c = 0.0f;
#pragma unroll
        for (int k = 0; k < 16; ++k) {
            float w = Wih0[r * 16 + k];
            a += w * Wtp[k];
            c += w * btp[k];
        }
        ws[r]       = a;
        ws[128 + r] = c + bih0[r] + bhh0[r];
        ws[256 + r] = bih1[r] + bhh1[r];
    }
}

__global__ __launch_bounds__(BS) void lstm_kernel(
    const float* __restrict__ x,
    const float* __restrict__ Whh0,   // [128,32]
    const float* __restrict__ Wih1,   // [128,32]
    const float* __restrict__ Whh1,   // [128,32]
    const float* __restrict__ Wfc1,   // [32,16]
    const float* __restrict__ bfc1,   // [16]
    const float* __restrict__ Wfc2,   // [16]
    const float* __restrict__ bfc2,   // [1]
    const float* __restrict__ pre,    // [384] from precomp
    float* __restrict__ out, int N)
{
    // c-state: partitioned, each wave owns its j-range columns (owner-only
    // access, no sync). snhA/snhB: h staged by producers, read by ALL
    // threads. Index [j*NPB + node]: consecutive lanes -> consecutive
    // banks (2 lanes/bank for wave64 = free).
    __shared__ float sc0 [32 * NPB];
    __shared__ float sc1 [32 * NPB];
    __shared__ float snhA[32 * NPB];   // layer-0 new h
    __shared__ float snhB[32 * NPB];   // layer-1 new h

    const int tid  = threadIdx.x;
    const int node = tid & (NPB - 1);
    // Wave-uniform gate-row base, FORCED into an SGPR so weight addresses
    // take the scalar-load (K$) path instead of per-lane vector loads.
    const int jbase = __builtin_amdgcn_readfirstlane((tid >> 6) * NJ);
    const int n  = blockIdx.x * NPB + node;
    const int nn = (n < N) ? n : (N > 0 ? N - 1 : 0);
    const float* xr = x + (size_t)nn * 64 + 52;   // last 12 features

    float h0[32], h1[32];
#pragma unroll
    for (int k = 0; k < 32; ++k) { h0[k] = 0.0f; h1[k] = 0.0f; }
#pragma unroll
    for (int jj = 0; jj < NJ; ++jj) {             // owner-only init, no sync
        sc0[(jbase + jj) * NPB + node] = 0.0f;
        sc1[(jbase + jj) * NPB + node] = 0.0f;
    }

#pragma unroll 1
    for (int t = 0; t < TSTEPS; ++t) {
        const float xval = xr[t];

        // ---------------- layer 0 (this wave's 8 gate rows) -------------
#pragma unroll 1
        for (int jj = 0; jj < NJ; ++jj) {
            const int j = jbase + jj;             // SGPR-resident
            float gi = pre[128 + j] + xval * pre[j];
            float gf = pre[160 + j] + xval * pre[32 + j];
            float gg = pre[192 + j] + xval * pre[64 + j];
            float go = pre[224 + j] + xval * pre[96 + j];
            const float* w = Whh0 + j * 32;       // rows j, j+32, j+64, j+96
#pragma unroll
            for (int k = 0; k < 32; ++k) {
                const float hk = h0[k];
                gi += w[k]        * hk;
                gf += w[1024 + k] * hk;
                gg += w[2048 + k] * hk;
                go += w[3072 + k] * hk;
            }
            const int ci = j * NPB + node;
            const float cc = fsig(gf) * sc0[ci] + fsig(gi) * ftanh(gg);
            sc0[ci]  = cc;
            snhA[ci] = fsig(go) * ftanh(cc);
        }
        __syncthreads();                           // snhA complete
#pragma unroll
        for (int k = 0; k < 32; ++k) h0[k] = snhA[k * NPB + node];

        // ---------------- layer 1 (this wave's 8 gate rows) -------------
#pragma unroll 1
        for (int jj = 0; jj < NJ; ++jj) {
            const int j = jbase + jj;
            float gi = pre[256 + j];
            float gf = pre[288 + j];
            float gg = pre[320 + j];
            float go = pre[352 + j];
            const float* wi = Wih1 + j * 32;
            const float* wh = Whh1 + j * 32;
#pragma unroll
            for (int k = 0; k < 32; ++k) {
                const float ak = h0[k];
                const float bk = h1[k];
                gi += wi[k]        * ak + wh[k]        * bk;
                gf += wi[1024 + k] * ak + wh[1024 + k] * bk;
                gg += wi[2048 + k] * ak + wh[2048 + k] * bk;
                go += wi[3072 + k] * ak + wh[3072 + k] * bk;
            }
            const int ci = j * NPB + node;
            const float cc = fsig(gf) * sc1[ci] + fsig(gi) * ftanh(gg);
            sc1[ci]  = cc;
            snhB[ci] = fsig(go) * ftanh(cc);
        }
        __syncthreads();                           // snhB complete; also
                                                   // fences snhA reads vs
                                                   // next-t layer-0 writes
#pragma unroll
        for (int k = 0; k < 32; ++k) h1[k] = snhB[k * NPB + node];
        // snhB reads vs next-t layer-1 writes are fenced by the next
        // iteration's first barrier.
    }

    // epilogue: relu(h1 @ Wfc1 + bfc1) @ Wfc2 + bfc2 — wave 0 only
    // (h1 is replicated in every thread's registers)
    if (tid < NPB) {
        float acc = bfc2[0];
#pragma unroll 1
        for (int m = 0; m < 16; ++m) {
            float a = bfc1[m];
#pragma unroll
            for (int k = 0; k < 32; ++k) a += h1[k] * Wfc1[k * 16 + m];
            acc += fmaxf(a, 0.0f) * Wfc2[m];
        }
        if (n < N) out[n] = acc;
    }
}

extern "C" void kernel_launch(void* const* d_in, const int* in_sizes, int n_in,
                              void* d_out, int out_size, void* d_ws, size_t ws_size,
                              hipStream_t stream) {
    (void)n_in; (void)out_size; (void)ws_size;
    // setup_inputs() order:
    // 0 x, 1 edge_index, 2 W_fp, 3 b_fp, 4 W_g1, 5 b_g1, 6 W_g2, 7 b_g2,
    // 8 W_g3, 9 b_g3, 10 W_tp, 11 b_tp, 12 Wih0, 13 Whh0, 14 bih0, 15 bhh0,
    // 16 Wih1, 17 Whh1, 18 bih1, 19 bhh1, 20 W_fc1, 21 b_fc1, 22 W_fc2, 23 b_fc2
    const float* x    = (const float*)d_in[0];
    const float* Wtp  = (const float*)d_in[10];
    const float* btp  = (const float*)d_in[11];
    const float* Wih0 = (const float*)d_in[12];
    const float* Whh0 = (const float*)d_in[13];
    const float* bih0 = (const float*)d_in[14];
    const float* bhh0 = (const float*)d_in[15];
    const float* Wih1 = (const float*)d_in[16];
    const float* Whh1 = (const float*)d_in[17];
    const float* bih1 = (const float*)d_in[18];
    const float* bhh1 = (const float*)d_in[19];
    const float* Wfc1 = (const float*)d_in[20];
    const float* bfc1 = (const float*)d_in[21];
    const float* Wfc2 = (const float*)d_in[22];
    const float* bfc2 = (const float*)d_in[23];

    float* out = (float*)d_out;
    float* pre = (float*)d_ws;   // 384 floats

    const int N = in_sizes[0] / 64;

    precomp_kernel<<<1, 128, 0, stream>>>(Wih0, Wtp, btp, bih0, bhh0, bih1, bhh1, pre);
    lstm_kernel<<<(N + NPB - 1) / NPB, BS, 0, stream>>>(
        x, Whh0, Wih1, Whh1, Wfc1, bfc1, Wfc2, bfc2, pre, out, N);
}